// Round 1
// baseline (1963.995 us; speedup 1.0000x reference)
//
#include <hip/hip_runtime.h>
#include <cstdint>
#include <cstddef>

typedef unsigned short u16;
typedef __attribute__((ext_vector_type(8))) short bf16x8;
typedef __attribute__((ext_vector_type(4))) float f32x4;

#define NB 256
#define LL 128
#define DD 1024
#define HH 512
#define GG 2048   // 4H
#define NN 4096   // 2*GG
#define LINN 512

__device__ __forceinline__ u16 f2bf(float f) {
  unsigned u = __float_as_uint(f);
  u += 0x7fffu + ((u >> 16) & 1u);
  return (u16)(u >> 16);
}
__device__ __forceinline__ float bf2f(u16 h) {
  return __uint_as_float(((unsigned)h) << 16);
}
__device__ __forceinline__ float sigm(float x) { return 1.0f / (1.0f + __expf(-x)); }
__device__ __forceinline__ float tanh_fast(float x) {
  float a = fabsf(x);
  float e = __expf(-2.0f * a);
  float t = (1.0f - e) / (1.0f + e);
  return copysignf(t, x);
}
__device__ __forceinline__ void load_lds16(const void* g, void* l) {
  __builtin_amdgcn_global_load_lds(
      (const __attribute__((address_space(1))) void*)g,
      (__attribute__((address_space(3))) void*)l, 16, 0, 0);
}

// ---------------- K1: fp32 -> bf16 convert of x ----------------
__global__ __launch_bounds__(256) void conv_bf16(const float* __restrict__ in,
                                                 u16* __restrict__ out) {
  size_t i = ((size_t)blockIdx.x * 256 + threadIdx.x) * 8;
  float4 a = *(const float4*)(in + i);
  float4 b = *(const float4*)(in + i + 4);
  uint4 v;
  v.x = (unsigned)f2bf(a.x) | ((unsigned)f2bf(a.y) << 16);
  v.y = (unsigned)f2bf(a.z) | ((unsigned)f2bf(a.w) << 16);
  v.z = (unsigned)f2bf(b.x) | ((unsigned)f2bf(b.y) << 16);
  v.w = (unsigned)f2bf(b.z) | ((unsigned)f2bf(b.w) << 16);
  *(uint4*)(out + i) = v;
}

// ---------------- K2: permute+convert weights ----------------
// permuted row p = 4*j + gate  <-  original row gate*512 + j   (gate: 0=i,1=f,2=g,3=o)
__global__ __launch_bounds__(256) void prep_weights(
    const float* __restrict__ Wih_f, const float* __restrict__ Whh_f, const float* __restrict__ b_f,
    const float* __restrict__ Wih_b, const float* __restrict__ Whh_b, const float* __restrict__ b_b,
    u16* __restrict__ Wih_p, u16* __restrict__ Whh_p, float* __restrict__ bias_p) {
  int idx = blockIdx.x * 256 + threadIdx.x;   // 0 .. 2048*1024-1
  int p = idx >> 10, k = idx & 1023;
  int src = ((p & 3) << 9) | (p >> 2);
  Wih_p[(size_t)p * DD + k] = f2bf(Wih_f[(size_t)src * DD + k]);
  Wih_p[(size_t)GG * DD + (size_t)p * DD + k] = f2bf(Wih_b[(size_t)src * DD + k]);
  if (k < HH) {
    Whh_p[(size_t)p * HH + k] = f2bf(Whh_f[(size_t)src * HH + k]);
    Whh_p[(size_t)GG * HH + (size_t)p * HH + k] = f2bf(Whh_b[(size_t)src * HH + k]);
  }
  if (k == 0) { bias_p[p] = b_f[src]; bias_p[GG + p] = b_b[src]; }
}

// ---------------- K3: attention scores + masked softmax ----------------
__global__ __launch_bounds__(256) void attn_alpha(
    const float* __restrict__ x, const float* __restrict__ tword,
    const float* __restrict__ W_h, const float* __restrict__ b_tanh,
    const int* __restrict__ xlen, float* __restrict__ alpha) {
  int b = blockIdx.x, tid = threadIdx.x;
  int lane = tid & 63, wave = tid >> 6;
  __shared__ float wred[4];
  __shared__ float uvals[LL];
  const float* tw = tword + (size_t)b * 5 * DD;
  float acc = 0.f;
  for (int i = tid; i < 5 * DD; i += 256) acc += tw[i] * W_h[DD + (i & (DD - 1))];
  #pragma unroll
  for (int off = 32; off; off >>= 1) acc += __shfl_down(acc, off);
  if (lane == 0) wred[wave] = acc;
  __syncthreads();
  float twdot = (wred[0] + wred[1] + wred[2] + wred[3]) * 0.2f;  // mean over 5 words
  int len = xlen[b];
  const float* xb = x + (size_t)b * LL * DD;
  for (int l = wave; l < LL; l += 4) {
    float s = 0.f;
    if (l < len) {
      const float* xr = xb + (size_t)l * DD;
      for (int k = lane * 4; k < DD; k += 256) {
        float4 xv = *(const float4*)(xr + k);
        float4 wv = *(const float4*)(W_h + k);
        s += xv.x * wv.x + xv.y * wv.y + xv.z * wv.z + xv.w * wv.w;
      }
      #pragma unroll
      for (int off = 32; off; off >>= 1) s += __shfl_down(s, off);
    }
    if (lane == 0) uvals[l] = (l < len) ? (s + twdot + b_tanh[l]) : -1000000.0f;
  }
  __syncthreads();
  if (wave == 0) {
    float u0 = uvals[lane], u1 = uvals[lane + 64];
    float m = fmaxf(u0, u1);
    #pragma unroll
    for (int off = 32; off; off >>= 1) m = fmaxf(m, __shfl_down(m, off));
    m = __shfl(m, 0);
    float e0 = __expf(u0 - m), e1 = __expf(u1 - m);
    float ssum = e0 + e1;
    #pragma unroll
    for (int off = 32; off; off >>= 1) ssum += __shfl_down(ssum, off);
    ssum = __shfl(ssum, 0);
    alpha[(size_t)b * LL + lane] = e0 / ssum;
    alpha[(size_t)b * LL + lane + 64] = e1 / ssum;
  }
}

// ---------------- K4: big input-projection GEMM ----------------
// C[m][n] = sum_k A[m][k]*Bw[n][k];  M=32768 (b*L+t), N=4096 (dir*2048+p), K=1024.
// 128x128 tile / block, BK=64, global_load_lds(16B), XOR-swizzled LDS.
__global__ __launch_bounds__(256) void gemm_bt(
    const u16* __restrict__ A, const u16* __restrict__ Bw, u16* __restrict__ C) {
  __shared__ u16 At[128 * 64];
  __shared__ u16 Bt[128 * 64];
  const int tid = threadIdx.x;
  const int lane = tid & 63, wave = tid >> 6;
  const int m0 = blockIdx.y * 128, n0 = blockIdx.x * 128;
  const int wm = (wave >> 1) * 64, wn = (wave & 1) * 64;
  const int l15 = lane & 15, quad = lane >> 4;
  f32x4 acc[4][4] = {};
  const int rs = tid >> 3;
  const int slot = tid & 7;
  for (int kt = 0; kt < 16; ++kt) {
    __syncthreads();
    #pragma unroll
    for (int cc = 0; cc < 4; ++cc) {
      int row = cc * 32 + rs;
      int kseg = slot ^ (row & 7);          // XOR swizzle (involution)
      const u16* ga = A + (size_t)(m0 + row) * DD + kt * 64 + kseg * 8;
      const u16* gb = Bw + (size_t)(n0 + row) * DD + kt * 64 + kseg * 8;
      load_lds16(ga, (char*)At + cc * 4096 + tid * 16);
      load_lds16(gb, (char*)Bt + cc * 4096 + tid * 16);
    }
    __syncthreads();
    #pragma unroll
    for (int ks = 0; ks < 2; ++ks) {
      bf16x8 av[4], bv[4];
      int kq = ks * 4 + quad;
      #pragma unroll
      for (int i = 0; i < 4; ++i) {
        int row = wm + i * 16 + l15;
        av[i] = *(const bf16x8*)(At + row * 64 + (kq ^ (row & 7)) * 8);
      }
      #pragma unroll
      for (int j = 0; j < 4; ++j) {
        int row = wn + j * 16 + l15;
        bv[j] = *(const bf16x8*)(Bt + row * 64 + (kq ^ (row & 7)) * 8);
      }
      #pragma unroll
      for (int i = 0; i < 4; ++i)
        #pragma unroll
        for (int j = 0; j < 4; ++j)
          acc[i][j] = __builtin_amdgcn_mfma_f32_16x16x32_bf16(av[i], bv[j], acc[i][j], 0, 0, 0);
    }
  }
  #pragma unroll
  for (int i = 0; i < 4; ++i) {
    #pragma unroll
    for (int r = 0; r < 4; ++r) {
      size_t row = (size_t)(m0 + wm + i * 16 + quad * 4 + r);
      u16* crow = C + row * NN + n0 + wn + l15;
      #pragma unroll
      for (int j = 0; j < 4; ++j) crow[j * 16] = f2bf(acc[i][j][r]);
    }
  }
}

// ---------------- K5: one recurrent step (both directions) ----------------
// block = (dir, btile of 64 batches, ntile of 64 permuted gate cols = 16 hidden units)
__global__ __launch_bounds__(256) void lstm_step(
    const u16* __restrict__ P, const u16* __restrict__ Whh_p,
    const float* __restrict__ bias_p, const float* __restrict__ alpha,
    const int* __restrict__ xlen, const u16* __restrict__ h_in,
    u16* __restrict__ h_out, float* __restrict__ cst,
    float* __restrict__ ctx, int s) {
  __shared__ u16 Wt[64][136];      // +8 pad: break 256B stride bank conflicts
  __shared__ u16 Ht[64][136];
  __shared__ float gbuf[64][68];
  const int tid = threadIdx.x;
  const int lane = tid & 63, wave = tid >> 6;
  const int l15 = lane & 15, quad = lane >> 4;
  const int bid = blockIdx.x;
  const int dir = bid >> 7, btile = (bid >> 5) & 3, ntile = bid & 31;
  const u16* Wbase = Whh_p + ((size_t)dir * GG + ntile * 64) * HH;
  const u16* Hbase = h_in + ((size_t)dir * NB + btile * 64) * HH;
  f32x4 acc[4] = {};
  for (int kc = 0; kc < 4; ++kc) {
    __syncthreads();
    #pragma unroll
    for (int it = 0; it < 4; ++it) {
      int idx = tid + it * 256;
      int row = idx >> 4, seg = idx & 15;
      *(uint4*)&Wt[row][seg * 8] = *(const uint4*)(Wbase + (size_t)row * HH + kc * 128 + seg * 8);
      *(uint4*)&Ht[row][seg * 8] = *(const uint4*)(Hbase + (size_t)row * HH + kc * 128 + seg * 8);
    }
    __syncthreads();
    #pragma unroll
    for (int ks = 0; ks < 4; ++ks) {
      int koff = ks * 32 + quad * 8;
      bf16x8 av = *(const bf16x8*)&Ht[wave * 16 + l15][koff];
      #pragma unroll
      for (int nt = 0; nt < 4; ++nt) {
        bf16x8 bv = *(const bf16x8*)&Wt[nt * 16 + l15][koff];
        acc[nt] = __builtin_amdgcn_mfma_f32_16x16x32_bf16(av, bv, acc[nt], 0, 0, 0);
      }
    }
  }
  __syncthreads();
  #pragma unroll
  for (int nt = 0; nt < 4; ++nt)
    #pragma unroll
    for (int r = 0; r < 4; ++r)
      gbuf[wave * 16 + quad * 4 + r][nt * 16 + l15] = acc[nt][r];
  __syncthreads();
  // gate phase: thread handles (b_local = tid>>2, jj = tid&3 + 4*it)
  const int b_local = tid >> 2;
  const int b_global = btile * 64 + b_local;
  const int len = xlen[b_global];
  int t_b = (dir == 0) ? s : (len - 1 - s);
  const bool valid = (s < len);
  if (t_b < 0) t_b = 0;
  const float al = alpha[(size_t)b_global * LL + t_b];
  const u16* Prow = P + ((size_t)b_global * LL + t_b) * NN + (size_t)dir * GG;
  #pragma unroll
  for (int it = 0; it < 4; ++it) {
    int jj = (tid & 3) + it * 4;
    int jg = ntile * 16 + jj;
    float4 gv = *(const float4*)&gbuf[b_local][4 * jj];
    const u16* pv = Prow + 4 * jg;
    const float* bp = bias_p + (size_t)dir * GG + 4 * jg;
    float gi = gv.x + bf2f(pv[0]) + bp[0];
    float gf = gv.y + bf2f(pv[1]) + bp[1];
    float gz = gv.z + bf2f(pv[2]) + bp[2];
    float go = gv.w + bf2f(pv[3]) + bp[3];
    float ig = sigm(gi), fg = sigm(gf), zg = tanh_fast(gz), og = sigm(go);
    size_t sidx = ((size_t)dir * NB + b_global) * HH + jg;
    float cp = cst[sidx];
    float cn = fg * cp + ig * zg;
    float hn = og * tanh_fast(cn);
    if (valid) {
      cst[sidx] = cn;
      h_out[sidx] = f2bf(hn);
      ctx[(size_t)b_global * (2 * HH) + (size_t)dir * HH + jg] += al * hn;
    } else {
      h_out[sidx] = h_in[sidx];   // carry h across the double buffer
    }
  }
}

// ---------------- K6: head: relu(ctx @ W_lin.T + b_lin) @ W_out.T + b_out ----------------
__global__ __launch_bounds__(256) void head(
    const float* __restrict__ ctx, const float* __restrict__ W_lin,
    const float* __restrict__ b_lin, const float* __restrict__ W_out,
    const float* __restrict__ b_out, float* __restrict__ out) {
  int b = blockIdx.x, tid = threadIdx.x;
  __shared__ float cbuf[2 * HH];
  __shared__ float lbuf[LINN];
  *(float4*)&cbuf[tid * 4] = *(const float4*)&ctx[(size_t)b * (2 * HH) + tid * 4];
  __syncthreads();
  #pragma unroll
  for (int rr = 0; rr < 2; ++rr) {
    int row = tid + rr * 256;
    const float* wr = W_lin + (size_t)row * (2 * HH);
    float s = 0.f;
    for (int k = 0; k < 2 * HH; k += 4) {
      float4 wv = *(const float4*)(wr + k);
      float4 cv = *(const float4*)(cbuf + k);
      s += wv.x * cv.x + wv.y * cv.y + wv.z * cv.z + wv.w * cv.w;
    }
    lbuf[row] = fmaxf(s + b_lin[row], 0.0f);
  }
  __syncthreads();
  int lane = tid & 63, wave = tid >> 6;
  if (wave < 3) {
    const float* wo = W_out + (size_t)wave * LINN;
    float s = 0.f;
    for (int k = lane; k < LINN; k += 64) s += lbuf[k] * wo[k];
    #pragma unroll
    for (int off = 32; off; off >>= 1) s += __shfl_down(s, off);
    if (lane == 0) out[(size_t)b * 3 + wave] = s + b_out[wave];
  }
}

extern "C" void kernel_launch(void* const* d_in, const int* in_sizes, int n_in,
                              void* d_out, int out_size, void* d_ws, size_t ws_size,
                              hipStream_t stream) {
  (void)in_sizes; (void)n_in; (void)out_size; (void)ws_size;
  const float* x      = (const float*)d_in[0];
  const int*   xlen   = (const int*)d_in[1];
  const float* tword  = (const float*)d_in[3];
  const float* Wih_f  = (const float*)d_in[5];
  const float* Whh_f  = (const float*)d_in[6];
  const float* b_f    = (const float*)d_in[7];
  const float* Wih_b  = (const float*)d_in[8];
  const float* Whh_b  = (const float*)d_in[9];
  const float* b_b    = (const float*)d_in[10];
  const float* W_h    = (const float*)d_in[11];
  const float* b_tanh = (const float*)d_in[12];
  const float* W_lin  = (const float*)d_in[13];
  const float* b_lin  = (const float*)d_in[14];
  const float* W_out  = (const float*)d_in[15];
  const float* b_out  = (const float*)d_in[16];
  float* out = (float*)d_out;

  char* w = (char*)d_ws;
  u16* xe_bf = (u16*)w;      w += (size_t)NB * LL * DD * 2;     // 64 MB
  u16* Pbuf  = (u16*)w;      w += (size_t)NB * LL * NN * 2;     // 256 MB
  u16* Wih_p = (u16*)w;      w += (size_t)2 * GG * DD * 2;      // 8 MB
  u16* Whh_p = (u16*)w;      w += (size_t)2 * GG * HH * 2;      // 4 MB
  float* bias_p = (float*)w; w += (size_t)2 * GG * 4;
  float* alphaW = (float*)w; w += (size_t)NB * LL * 4;
  u16* hbuf0 = (u16*)w;      w += (size_t)2 * NB * HH * 2;
  u16* hbuf1 = (u16*)w;      w += (size_t)2 * NB * HH * 2;
  float* cbuf = (float*)w;   w += (size_t)2 * NB * HH * 4;
  float* ctxb = (float*)w;   w += (size_t)NB * 2 * HH * 4;

  hipMemsetAsync(hbuf0, 0, (size_t)2 * NB * HH * 2, stream);
  hipMemsetAsync(cbuf, 0, (size_t)2 * NB * HH * 4, stream);
  hipMemsetAsync(ctxb, 0, (size_t)NB * 2 * HH * 4, stream);

  conv_bf16<<<16384, 256, 0, stream>>>(x, xe_bf);
  prep_weights<<<8192, 256, 0, stream>>>(Wih_f, Whh_f, b_f, Wih_b, Whh_b, b_b,
                                         Wih_p, Whh_p, bias_p);
  attn_alpha<<<256, 256, 0, stream>>>(x, tword, W_h, b_tanh, xlen, alphaW);
  gemm_bt<<<dim3(32, 256), 256, 0, stream>>>(xe_bf, Wih_p, Pbuf);
  for (int s = 0; s < LL; ++s) {
    u16* hi = (s & 1) ? hbuf1 : hbuf0;
    u16* ho = (s & 1) ? hbuf0 : hbuf1;
    lstm_step<<<256, 256, 0, stream>>>(Pbuf, Whh_p, bias_p, alphaW, xlen,
                                       hi, ho, cbuf, ctxb, s);
  }
  head<<<256, 256, 0, stream>>>(ctxb, W_lin, b_lin, W_out, b_out, out);
}